// Round 1
// baseline (702.273 us; speedup 1.0000x reference)
//
#include <hip/hip_runtime.h>

typedef __bf16 bf16;
typedef __attribute__((ext_vector_type(8))) __bf16 bf16x8;
typedef __attribute__((ext_vector_type(4))) float f32x4;

// ---------------------------------------------------------------- utilities

__device__ __forceinline__ unsigned short f2bf(float f) {
    union { float f; unsigned u; } v; v.f = f;
    unsigned r = v.u + 0x7FFFu + ((v.u >> 16) & 1u);   // RNE
    return (unsigned short)(r >> 16);
}

// Stage a 128-row x 64-bf16 (128 B/row) tile from global into LDS via
// global_load_lds width=16. 256 threads x 4 reps x 16 B = 16 KB.
// LDS layout: row-major [128][64] bf16, contiguous (no padding: required by
// the wave-uniform-base + lane*16 semantics of global_load_lds).
__device__ __forceinline__ void stage128x64(const bf16* g, int ld_elems,
                                            bf16* lds, int tid) {
    const char* gb = (const char*)g;
    const int ldb = ld_elems * 2;
#pragma unroll
    for (int r = 0; r < 4; ++r) {
        int lin = r * 256 + tid;          // 0..1023, lane-contiguous per wave
        int row = lin >> 3;               // 8 x 16B chunks per 128 B row
        int ch  = lin & 7;
        __builtin_amdgcn_global_load_lds(
            (const __attribute__((address_space(1))) void*)(gb + (size_t)row * ldb + ch * 16),
            (__attribute__((address_space(3))) void*)(lds + lin * 8),
            16, 0, 0);
    }
}

// One BK=64 step: 4 waves in 2x2; each wave computes a 64x64 tile as 4x4
// MFMA 16x16x32 tiles. A-frag: A[m=lane&15][k=(lane>>4)*8..+8]; B operand is
// B^T rows (n-major, k-contiguous) with identical lane layout.
__device__ __forceinline__ void mma_tile(const bf16* As, const bf16* Bs,
                                         int wm, int wn, int lane,
                                         f32x4 acc[4][4]) {
    const int lm = lane & 15;
    const int lk = (lane >> 4) * 8;
#pragma unroll
    for (int ks = 0; ks < 2; ++ks) {
        bf16x8 a[4], b[4];
#pragma unroll
        for (int t = 0; t < 4; ++t)
            a[t] = *(const bf16x8*)(As + (wm * 64 + t * 16 + lm) * 64 + ks * 32 + lk);
#pragma unroll
        for (int t = 0; t < 4; ++t)
            b[t] = *(const bf16x8*)(Bs + (wn * 64 + t * 16 + lm) * 64 + ks * 32 + lk);
#pragma unroll
        for (int i = 0; i < 4; ++i)
#pragma unroll
            for (int j = 0; j < 4; ++j)
                acc[i][j] = __builtin_amdgcn_mfma_f32_16x16x32_bf16(a[i], b[j], acc[i][j], 0, 0, 0);
    }
}

// ---------------------------------------------------------------- kernels

// fp32 -> bf16 for x, Wq, Wk, Wo; also zeroes Z (65536 floats).
__global__ void convert_kernel(const float* __restrict__ x,  const float* __restrict__ Wq,
                               const float* __restrict__ Wk, const float* __restrict__ Wo,
                               unsigned short* xb, unsigned short* Wqb,
                               unsigned short* Wkb, unsigned short* Wob,
                               float* Z) {
    size_t i = ((size_t)blockIdx.x * 256 + threadIdx.x) * 4;
    if (i >= 7340032) {                       // tail region: zero Z
        if (i < 7405568) {
            float4 z = make_float4(0.f, 0.f, 0.f, 0.f);
            *(float4*)(Z + (i - 7340032)) = z;
        }
        return;
    }
    const float* src; unsigned short* dst; size_t off;
    if      (i < 4194304) { src = x;  dst = xb;  off = i; }
    else if (i < 5242880) { src = Wq; dst = Wqb; off = i - 4194304; }
    else if (i < 6291456) { src = Wk; dst = Wkb; off = i - 5242880; }
    else                  { src = Wo; dst = Wob; off = i - 6291456; }
    float4 v = *(const float4*)(src + off);
    ushort4 o;
    o.x = f2bf(v.x); o.y = f2bf(v.y); o.z = f2bf(v.z); o.w = f2bf(v.w);
    *(ushort4*)(dst + off) = o;
}

// Q = Xb @ Wq^T + bq, K = Xb @ Wk^T + bk  (blockIdx.z selects Q or K).
// M=4096, N=1024, K=1024. Output bf16 [4096][1024].
__global__ __launch_bounds__(256) void proj_kernel(
        const bf16* __restrict__ X, const bf16* __restrict__ Wqb,
        const bf16* __restrict__ Wkb, const float* __restrict__ bq,
        const float* __restrict__ bk, unsigned short* Qb, unsigned short* Kb) {
    __shared__ bf16 As[128 * 64];
    __shared__ bf16 Bs[128 * 64];
    const int tid = threadIdx.x, wid = tid >> 6, lane = tid & 63;
    const int wm = wid >> 1, wn = wid & 1;
    const int n0 = blockIdx.x * 128, m0 = blockIdx.y * 128;
    const bf16*  W    = blockIdx.z ? Wkb : Wqb;
    const float* bias = blockIdx.z ? bk  : bq;
    unsigned short* Out = blockIdx.z ? Kb : Qb;

    f32x4 acc[4][4];
    const f32x4 z4 = {0.f, 0.f, 0.f, 0.f};
#pragma unroll
    for (int i = 0; i < 4; ++i)
#pragma unroll
        for (int j = 0; j < 4; ++j) acc[i][j] = z4;

    for (int kt = 0; kt < 16; ++kt) {
        stage128x64(X + (size_t)m0 * 1024 + kt * 64, 1024, As, tid);
        stage128x64(W + (size_t)n0 * 1024 + kt * 64, 1024, Bs, tid);
        __syncthreads();
        mma_tile(As, Bs, wm, wn, lane, acc);
        __syncthreads();
    }

    const int q = lane >> 4, lm = lane & 15;
#pragma unroll
    for (int j = 0; j < 4; ++j) {
        const int col = n0 + wn * 64 + j * 16 + lm;
        const float bc = bias[col];
#pragma unroll
        for (int i = 0; i < 4; ++i)
#pragma unroll
            for (int r = 0; r < 4; ++r) {
                const int row = m0 + wm * 64 + i * 16 + q * 4 + r;
                Out[(size_t)row * 1024 + col] = f2bf(acc[i][j][r] + bc);
            }
    }
}

// Per (b,h): S-tile = Q K^T / 8; Pun = exp(s)*maskbit (bf16, stored at final
// GEMM row m = b*16384 + i*16 + h); Z[m] += row sums (fp32 atomics).
__global__ __launch_bounds__(256) void scores_kernel(
        const bf16* __restrict__ Qb, const bf16* __restrict__ Kb,
        const int* __restrict__ mask, unsigned short* Pun, float* Z) {
    __shared__ bf16 As[128 * 64];
    __shared__ bf16 Bs[128 * 64];
    const int tid = threadIdx.x, wid = tid >> 6, lane = tid & 63;
    const int wm = wid >> 1, wn = wid & 1;
    const int j0 = blockIdx.x * 128, i0 = blockIdx.y * 128;
    const int h = blockIdx.z & 15, b = blockIdx.z >> 4;

    const bf16* A  = Qb + ((size_t)(b * 1024 + i0)) * 1024 + h * 64;
    const bf16* Bt = Kb + ((size_t)(b * 1024 + j0)) * 1024 + h * 64;

    f32x4 acc[4][4];
    const f32x4 z4 = {0.f, 0.f, 0.f, 0.f};
#pragma unroll
    for (int i = 0; i < 4; ++i)
#pragma unroll
        for (int j = 0; j < 4; ++j) acc[i][j] = z4;

    stage128x64(A, 1024, As, tid);
    stage128x64(Bt, 1024, Bs, tid);
    __syncthreads();
    mma_tile(As, Bs, wm, wn, lane, acc);

    const int q = lane >> 4, lm = lane & 15;
    float rs[4][4];
#pragma unroll
    for (int i = 0; i < 4; ++i)
#pragma unroll
        for (int r = 0; r < 4; ++r) rs[i][r] = 0.f;

#pragma unroll
    for (int i = 0; i < 4; ++i)
#pragma unroll
        for (int r = 0; r < 4; ++r) {
            const int ii = i0 + wm * 64 + i * 16 + q * 4 + r;
            const size_t mrow = (size_t)b * 16384 + (size_t)ii * 16 + h;
#pragma unroll
            for (int j = 0; j < 4; ++j) {
                const int jj = j0 + wn * 64 + j * 16 + lm;
                const float s = acc[i][j][r] * 0.125f;
                const int mk = mask[((size_t)b * 1024 + ii) * 1024 + jj];
                const float p = mk ? __expf(s) : 0.f;
                Pun[mrow * 1024 + jj] = f2bf(p);
                rs[i][r] += p;
            }
        }

    // reduce row partials across the 16 lanes of each quad-row group
#pragma unroll
    for (int i = 0; i < 4; ++i)
#pragma unroll
        for (int r = 0; r < 4; ++r) {
            float v = rs[i][r];
            for (int off = 1; off < 16; off <<= 1) v += __shfl_xor(v, off, 16);
            if (lm == 0) {
                const int ii = i0 + wm * 64 + i * 16 + q * 4 + r;
                atomicAdd(&Z[(size_t)b * 16384 + (size_t)ii * 16 + h], v);
            }
        }
}

__global__ void zinv_kernel(const float* __restrict__ Z, float* Zi) {
    const int i = blockIdx.x * 256 + threadIdx.x;
    Zi[i] = 1.0f / Z[i];
}

// out = (Pun @ Wo^T) * Zinv[m] + bo[e].  M=65536, N=1024, K=1024.
// Block swizzle: same-XCD consecutive blocks share an M-tile (Pun L2 reuse).
__global__ __launch_bounds__(256) void out_gemm_kernel(
        const bf16* __restrict__ Pun, const bf16* __restrict__ Wob,
        const float* __restrict__ Zi, const float* __restrict__ bo,
        float* __restrict__ out) {
    __shared__ bf16 As[128 * 64];
    __shared__ bf16 Bs[128 * 64];
    const int tid = threadIdx.x, wid = tid >> 6, lane = tid & 63;
    const int wm = wid >> 1, wn = wid & 1;
    const int bid = blockIdx.x;
    const int n0 = ((bid >> 3) & 7) * 128;
    const int m0 = ((bid & 7) + ((bid >> 6) << 3)) * 128;

    f32x4 acc[4][4];
    const f32x4 z4 = {0.f, 0.f, 0.f, 0.f};
#pragma unroll
    for (int i = 0; i < 4; ++i)
#pragma unroll
        for (int j = 0; j < 4; ++j) acc[i][j] = z4;

    for (int kt = 0; kt < 16; ++kt) {
        stage128x64(Pun + (size_t)m0 * 1024 + kt * 64, 1024, As, tid);
        stage128x64(Wob + (size_t)n0 * 1024 + kt * 64, 1024, Bs, tid);
        __syncthreads();
        mma_tile(As, Bs, wm, wn, lane, acc);
        __syncthreads();
    }

    const int q = lane >> 4, lm = lane & 15;
#pragma unroll
    for (int j = 0; j < 4; ++j) {
        const int col = n0 + wn * 64 + j * 16 + lm;
        const float bc = bo[col];
#pragma unroll
        for (int i = 0; i < 4; ++i)
#pragma unroll
            for (int r = 0; r < 4; ++r) {
                const int row = m0 + wm * 64 + i * 16 + q * 4 + r;
                out[(size_t)row * 1024 + col] = acc[i][j][r] * Zi[row] + bc;
            }
    }
}

// ---------------------------------------------------------------- launch

extern "C" void kernel_launch(void* const* d_in, const int* in_sizes, int n_in,
                              void* d_out, int out_size, void* d_ws, size_t ws_size,
                              hipStream_t stream) {
    (void)in_sizes; (void)n_in; (void)out_size; (void)ws_size;
    const float* x    = (const float*)d_in[0];
    const int*   mask = (const int*)d_in[1];
    const float* Wq   = (const float*)d_in[2];
    const float* bq   = (const float*)d_in[3];
    const float* Wk   = (const float*)d_in[4];
    const float* bk   = (const float*)d_in[5];
    // d_in[6]=Wv, d_in[7]=bv: computed-then-discarded in reference; skipped.
    const float* Wo   = (const float*)d_in[8];
    const float* bo   = (const float*)d_in[9];

    char* ws = (char*)d_ws;
    bf16*  xb  = (bf16*)(ws);                    //  8 MB  x bf16
    bf16*  Wqb = (bf16*)(ws + 8388608);          //  2 MB
    bf16*  Wkb = (bf16*)(ws + 10485760);         //  2 MB
    bf16*  Wob = (bf16*)(ws + 12582912);         //  2 MB
    bf16*  Qb  = (bf16*)(ws + 14680064);         //  8 MB
    bf16*  Kb  = (bf16*)(ws + 23068672);         //  8 MB
    float* Z   = (float*)(ws + 31457280);        // 256 KB
    float* Zi  = (float*)(ws + 31719424);        // 256 KB
    bf16*  Pun = (bf16*)(ws + 31981568);         // 128 MB (end ~158.5 MB)

    convert_kernel<<<7232, 256, 0, stream>>>(x, Wq, Wk, Wo,
        (unsigned short*)xb, (unsigned short*)Wqb, (unsigned short*)Wkb,
        (unsigned short*)Wob, Z);
    proj_kernel<<<dim3(8, 32, 2), 256, 0, stream>>>(xb, Wqb, Wkb, bq, bk,
        (unsigned short*)Qb, (unsigned short*)Kb);
    scores_kernel<<<dim3(8, 8, 64), 256, 0, stream>>>(Qb, Kb, mask,
        (unsigned short*)Pun, Z);
    zinv_kernel<<<256, 256, 0, stream>>>(Z, Zi);
    out_gemm_kernel<<<4096, 256, 0, stream>>>(Pun, Wob, Zi, bo, (float*)d_out);
}

// Round 2
// 659.471 us; speedup vs baseline: 1.0649x; 1.0649x over previous
//
#include <hip/hip_runtime.h>

typedef __bf16 bf16;
typedef __attribute__((ext_vector_type(8))) __bf16 bf16x8;
typedef __attribute__((ext_vector_type(4))) float f32x4;

// ---------------------------------------------------------------- utilities

__device__ __forceinline__ unsigned short f2bf(float f) {
    union { float f; unsigned u; } v; v.f = f;
    unsigned r = v.u + 0x7FFFu + ((v.u >> 16) & 1u);   // RNE
    return (unsigned short)(r >> 16);
}

// Stage a 128-row x 64-bf16 (128 B/row) tile from global into LDS via
// global_load_lds width=16. 256 threads x 4 reps x 16 B = 16 KB.
// LDS layout: row-major [128][64] bf16 with XOR-swizzled 16B chunks:
// row r's global chunk c lands at LDS chunk position c ^ (r&7). This breaks
// the 16-way bank conflict of the unswizzled 128B-row layout (R1: 5e7
// SQ_LDS_BANK_CONFLICT) while keeping the wave-uniform-base + lane*16
// semantics global_load_lds requires (no padding allowed).
__device__ __forceinline__ void stage128x64(const bf16* g, int ld_elems,
                                            bf16* lds, int tid) {
    const char* gb = (const char*)g;
    const int ldb = ld_elems * 2;
#pragma unroll
    for (int r = 0; r < 4; ++r) {
        int lin = r * 256 + tid;          // 0..1023, lane-contiguous per wave
        int row = lin >> 3;               // 8 x 16B chunks per 128 B row
        int ch  = (lin & 7) ^ (row & 7);  // XOR swizzle: global chunk for this slot
        __builtin_amdgcn_global_load_lds(
            (const __attribute__((address_space(1))) void*)(gb + (size_t)row * ldb + ch * 16),
            (__attribute__((address_space(3))) void*)(lds + lin * 8),
            16, 0, 0);
    }
}

// One BK=64 step: 4 waves in 2x2; each wave computes a 64x64 tile as 4x4
// MFMA 16x16x32 tiles. A-frag: A[m=lane&15][k=(lane>>4)*8..+8]; B operand is
// B^T rows (n-major, k-contiguous) with identical lane layout.
// Reads follow the XOR chunk swizzle: row r, 16B chunk c lives at c ^ (r&7).
__device__ __forceinline__ void mma_tile(const bf16* As, const bf16* Bs,
                                         int wm, int wn, int lane,
                                         f32x4 acc[4][4]) {
    const int lm = lane & 15;
    const int g  = lane >> 4;             // 16B chunk subgroup (0..3)
#pragma unroll
    for (int ks = 0; ks < 2; ++ks) {
        const int c = ks * 4 + g;         // logical 16B chunk within 128B row
        bf16x8 a[4], b[4];
#pragma unroll
        for (int t = 0; t < 4; ++t) {
            const int row = wm * 64 + t * 16 + lm;
            a[t] = *(const bf16x8*)(As + row * 64 + ((c ^ (row & 7)) << 3));
        }
#pragma unroll
        for (int t = 0; t < 4; ++t) {
            const int row = wn * 64 + t * 16 + lm;
            b[t] = *(const bf16x8*)(Bs + row * 64 + ((c ^ (row & 7)) << 3));
        }
#pragma unroll
        for (int i = 0; i < 4; ++i)
#pragma unroll
            for (int j = 0; j < 4; ++j)
                acc[i][j] = __builtin_amdgcn_mfma_f32_16x16x32_bf16(a[i], b[j], acc[i][j], 0, 0, 0);
    }
}

// ---------------------------------------------------------------- kernels

// fp32 -> bf16 for x, Wq, Wk, Wo; also zeroes Z (65536 floats).
__global__ void convert_kernel(const float* __restrict__ x,  const float* __restrict__ Wq,
                               const float* __restrict__ Wk, const float* __restrict__ Wo,
                               unsigned short* xb, unsigned short* Wqb,
                               unsigned short* Wkb, unsigned short* Wob,
                               float* Z) {
    size_t i = ((size_t)blockIdx.x * 256 + threadIdx.x) * 4;
    if (i >= 7340032) {                       // tail region: zero Z
        if (i < 7405568) {
            float4 z = make_float4(0.f, 0.f, 0.f, 0.f);
            *(float4*)(Z + (i - 7340032)) = z;
        }
        return;
    }
    const float* src; unsigned short* dst; size_t off;
    if      (i < 4194304) { src = x;  dst = xb;  off = i; }
    else if (i < 5242880) { src = Wq; dst = Wqb; off = i - 4194304; }
    else if (i < 6291456) { src = Wk; dst = Wkb; off = i - 5242880; }
    else                  { src = Wo; dst = Wob; off = i - 6291456; }
    float4 v = *(const float4*)(src + off);
    ushort4 o;
    o.x = f2bf(v.x); o.y = f2bf(v.y); o.z = f2bf(v.z); o.w = f2bf(v.w);
    *(ushort4*)(dst + off) = o;
}

// Q = Xb @ Wq^T + bq, K = Xb @ Wk^T + bk  (blockIdx.z selects Q or K).
// M=4096, N=1024, K=1024. Output bf16 [4096][1024].
__global__ __launch_bounds__(256) void proj_kernel(
        const bf16* __restrict__ X, const bf16* __restrict__ Wqb,
        const bf16* __restrict__ Wkb, const float* __restrict__ bq,
        const float* __restrict__ bk, unsigned short* Qb, unsigned short* Kb) {
    __shared__ bf16 As[128 * 64];
    __shared__ bf16 Bs[128 * 64];
    const int tid = threadIdx.x, wid = tid >> 6, lane = tid & 63;
    const int wm = wid >> 1, wn = wid & 1;
    const int n0 = blockIdx.x * 128, m0 = blockIdx.y * 128;
    const bf16*  W    = blockIdx.z ? Wkb : Wqb;
    const float* bias = blockIdx.z ? bk  : bq;
    unsigned short* Out = blockIdx.z ? Kb : Qb;

    f32x4 acc[4][4];
    const f32x4 z4 = {0.f, 0.f, 0.f, 0.f};
#pragma unroll
    for (int i = 0; i < 4; ++i)
#pragma unroll
        for (int j = 0; j < 4; ++j) acc[i][j] = z4;

    for (int kt = 0; kt < 16; ++kt) {
        stage128x64(X + (size_t)m0 * 1024 + kt * 64, 1024, As, tid);
        stage128x64(W + (size_t)n0 * 1024 + kt * 64, 1024, Bs, tid);
        __syncthreads();
        mma_tile(As, Bs, wm, wn, lane, acc);
        __syncthreads();
    }

    const int q = lane >> 4, lm = lane & 15;
#pragma unroll
    for (int j = 0; j < 4; ++j) {
        const int col = n0 + wn * 64 + j * 16 + lm;
        const float bc = bias[col];
#pragma unroll
        for (int i = 0; i < 4; ++i)
#pragma unroll
            for (int r = 0; r < 4; ++r) {
                const int row = m0 + wm * 64 + i * 16 + q * 4 + r;
                Out[(size_t)row * 1024 + col] = f2bf(acc[i][j][r] + bc);
            }
    }
}

// Per (b,h): S-tile = Q K^T / 8; Pun = exp(s)*maskbit (bf16, stored at final
// GEMM row m = b*16384 + i*16 + h); Z[m] += row sums (fp32 atomics).
__global__ __launch_bounds__(256) void scores_kernel(
        const bf16* __restrict__ Qb, const bf16* __restrict__ Kb,
        const int* __restrict__ mask, unsigned short* Pun, float* Z) {
    __shared__ bf16 As[128 * 64];
    __shared__ bf16 Bs[128 * 64];
    const int tid = threadIdx.x, wid = tid >> 6, lane = tid & 63;
    const int wm = wid >> 1, wn = wid & 1;
    const int j0 = blockIdx.x * 128, i0 = blockIdx.y * 128;
    const int h = blockIdx.z & 15, b = blockIdx.z >> 4;

    const bf16* A  = Qb + ((size_t)(b * 1024 + i0)) * 1024 + h * 64;
    const bf16* Bt = Kb + ((size_t)(b * 1024 + j0)) * 1024 + h * 64;

    f32x4 acc[4][4];
    const f32x4 z4 = {0.f, 0.f, 0.f, 0.f};
#pragma unroll
    for (int i = 0; i < 4; ++i)
#pragma unroll
        for (int j = 0; j < 4; ++j) acc[i][j] = z4;

    stage128x64(A, 1024, As, tid);
    stage128x64(Bt, 1024, Bs, tid);
    __syncthreads();
    mma_tile(As, Bs, wm, wn, lane, acc);

    const int q = lane >> 4, lm = lane & 15;
    float rs[4][4];
#pragma unroll
    for (int i = 0; i < 4; ++i)
#pragma unroll
        for (int r = 0; r < 4; ++r) rs[i][r] = 0.f;

#pragma unroll
    for (int i = 0; i < 4; ++i)
#pragma unroll
        for (int r = 0; r < 4; ++r) {
            const int ii = i0 + wm * 64 + i * 16 + q * 4 + r;
            const size_t mrow = (size_t)b * 16384 + (size_t)ii * 16 + h;
#pragma unroll
            for (int j = 0; j < 4; ++j) {
                const int jj = j0 + wn * 64 + j * 16 + lm;
                const float s = acc[i][j][r] * 0.125f;
                const int mk = mask[((size_t)b * 1024 + ii) * 1024 + jj];
                const float p = mk ? __expf(s) : 0.f;
                Pun[mrow * 1024 + jj] = f2bf(p);
                rs[i][r] += p;
            }
        }

    // reduce row partials across the 16 lanes of each quad-row group
#pragma unroll
    for (int i = 0; i < 4; ++i)
#pragma unroll
        for (int r = 0; r < 4; ++r) {
            float v = rs[i][r];
            for (int off = 1; off < 16; off <<= 1) v += __shfl_xor(v, off, 16);
            if (lm == 0) {
                const int ii = i0 + wm * 64 + i * 16 + q * 4 + r;
                atomicAdd(&Z[(size_t)b * 16384 + (size_t)ii * 16 + h], v);
            }
        }
}

// out = (Pun @ Wo^T) / Z[m] + bo[e].  M=65536, N=1024, K=1024.
// Block swizzle: same-XCD consecutive blocks share an M-tile (Pun L2 reuse).
// Zinv folded into the epilogue (one v_rcp per element; saves a kernel).
__global__ __launch_bounds__(256) void out_gemm_kernel(
        const bf16* __restrict__ Pun, const bf16* __restrict__ Wob,
        const float* __restrict__ Z, const float* __restrict__ bo,
        float* __restrict__ out) {
    __shared__ bf16 As[128 * 64];
    __shared__ bf16 Bs[128 * 64];
    const int tid = threadIdx.x, wid = tid >> 6, lane = tid & 63;
    const int wm = wid >> 1, wn = wid & 1;
    const int bid = blockIdx.x;
    const int n0 = ((bid >> 3) & 7) * 128;
    const int m0 = ((bid & 7) + ((bid >> 6) << 3)) * 128;

    f32x4 acc[4][4];
    const f32x4 z4 = {0.f, 0.f, 0.f, 0.f};
#pragma unroll
    for (int i = 0; i < 4; ++i)
#pragma unroll
        for (int j = 0; j < 4; ++j) acc[i][j] = z4;

    for (int kt = 0; kt < 16; ++kt) {
        stage128x64(Pun + (size_t)m0 * 1024 + kt * 64, 1024, As, tid);
        stage128x64(Wob + (size_t)n0 * 1024 + kt * 64, 1024, Bs, tid);
        __syncthreads();
        mma_tile(As, Bs, wm, wn, lane, acc);
        __syncthreads();
    }

    const int q = lane >> 4, lm = lane & 15;
#pragma unroll
    for (int i = 0; i < 4; ++i)
#pragma unroll
        for (int r = 0; r < 4; ++r) {
            const int row = m0 + wm * 64 + i * 16 + q * 4 + r;
            const float zi = 1.0f / Z[row];
#pragma unroll
            for (int j = 0; j < 4; ++j) {
                const int col = n0 + wn * 64 + j * 16 + lm;
                out[(size_t)row * 1024 + col] = acc[i][j][r] * zi + bo[col];
            }
        }
}

// ---------------------------------------------------------------- launch

extern "C" void kernel_launch(void* const* d_in, const int* in_sizes, int n_in,
                              void* d_out, int out_size, void* d_ws, size_t ws_size,
                              hipStream_t stream) {
    (void)in_sizes; (void)n_in; (void)out_size; (void)ws_size;
    const float* x    = (const float*)d_in[0];
    const int*   mask = (const int*)d_in[1];
    const float* Wq   = (const float*)d_in[2];
    const float* bq   = (const float*)d_in[3];
    const float* Wk   = (const float*)d_in[4];
    const float* bk   = (const float*)d_in[5];
    // d_in[6]=Wv, d_in[7]=bv: computed-then-discarded in reference; skipped.
    const float* Wo   = (const float*)d_in[8];
    const float* bo   = (const float*)d_in[9];

    char* ws = (char*)d_ws;
    bf16*  xb  = (bf16*)(ws);                    //  8 MB  x bf16
    bf16*  Wqb = (bf16*)(ws + 8388608);          //  2 MB
    bf16*  Wkb = (bf16*)(ws + 10485760);         //  2 MB
    bf16*  Wob = (bf16*)(ws + 12582912);         //  2 MB
    bf16*  Qb  = (bf16*)(ws + 14680064);         //  8 MB
    bf16*  Kb  = (bf16*)(ws + 23068672);         //  8 MB
    float* Z   = (float*)(ws + 31457280);        // 256 KB
    bf16*  Pun = (bf16*)(ws + 31981568);         // 128 MB (end ~158.5 MB)

    convert_kernel<<<7232, 256, 0, stream>>>(x, Wq, Wk, Wo,
        (unsigned short*)xb, (unsigned short*)Wqb, (unsigned short*)Wkb,
        (unsigned short*)Wob, Z);
    proj_kernel<<<dim3(8, 32, 2), 256, 0, stream>>>(xb, Wqb, Wkb, bq, bk,
        (unsigned short*)Qb, (unsigned short*)Kb);
    scores_kernel<<<dim3(8, 8, 64), 256, 0, stream>>>(Qb, Kb, mask,
        (unsigned short*)Pun, Z);
    out_gemm_kernel<<<4096, 256, 0, stream>>>(Pun, Wob, Z, bo, (float*)d_out);
}

// Round 3
// 649.878 us; speedup vs baseline: 1.0806x; 1.0148x over previous
//
#include <hip/hip_runtime.h>

typedef __bf16 bf16;
typedef __attribute__((ext_vector_type(8))) __bf16 bf16x8;
typedef __attribute__((ext_vector_type(4))) float f32x4;

// ---------------------------------------------------------------- utilities

__device__ __forceinline__ unsigned short f2bf(float f) {
    union { float f; unsigned u; } v; v.f = f;
    unsigned r = v.u + 0x7FFFu + ((v.u >> 16) & 1u);   // RNE
    return (unsigned short)(r >> 16);
}

// Stage a 128-row x 64-bf16 (128 B/row) tile from global into LDS via
// global_load_lds width=16. 256 threads x 4 reps x 16 B = 16 KB.
// XOR swizzle: row r's global 16B chunk c lands at LDS chunk c ^ (r&7)
// (breaks the 16-way bank conflict of the plain layout; R2 measured 0
// SQ_LDS_BANK_CONFLICT with this scheme).
__device__ __forceinline__ void stage128x64(const bf16* g, int ld_elems,
                                            bf16* lds, int tid) {
    const char* gb = (const char*)g;
    const int ldb = ld_elems * 2;
#pragma unroll
    for (int r = 0; r < 4; ++r) {
        int lin = r * 256 + tid;          // 0..1023, lane-contiguous per wave
        int row = lin >> 3;               // 8 x 16B chunks per 128 B row
        int ch  = (lin & 7) ^ (row & 7);  // XOR swizzle
        __builtin_amdgcn_global_load_lds(
            (const __attribute__((address_space(1))) void*)(gb + (size_t)row * ldb + ch * 16),
            (__attribute__((address_space(3))) void*)(lds + lin * 8),
            16, 0, 0);
    }
}

// 128x128 tile step (4 waves 2x2), BK=64. Used by proj and scores.
__device__ __forceinline__ void mma_tile(const bf16* As, const bf16* Bs,
                                         int wm, int wn, int lane,
                                         f32x4 acc[4][4]) {
    const int lm = lane & 15;
    const int g  = lane >> 4;
#pragma unroll
    for (int ks = 0; ks < 2; ++ks) {
        const int c = ks * 4 + g;
        bf16x8 a[4], b[4];
#pragma unroll
        for (int t = 0; t < 4; ++t) {
            const int row = wm * 64 + t * 16 + lm;
            a[t] = *(const bf16x8*)(As + row * 64 + ((c ^ (row & 7)) << 3));
        }
#pragma unroll
        for (int t = 0; t < 4; ++t) {
            const int row = wn * 64 + t * 16 + lm;
            b[t] = *(const bf16x8*)(Bs + row * 64 + ((c ^ (row & 7)) << 3));
        }
#pragma unroll
        for (int i = 0; i < 4; ++i)
#pragma unroll
            for (int j = 0; j < 4; ++j)
                acc[i][j] = __builtin_amdgcn_mfma_f32_16x16x32_bf16(a[i], b[j], acc[i][j], 0, 0, 0);
    }
}

// ---------------------------------------------------------------- kernels

// fp32 -> bf16 for x, Wq, Wk, Wo. (Z no longer needs zeroing: scores writes
// it directly now.)
__global__ void convert_kernel(const float* __restrict__ x,  const float* __restrict__ Wq,
                               const float* __restrict__ Wk, const float* __restrict__ Wo,
                               unsigned short* xb, unsigned short* Wqb,
                               unsigned short* Wkb, unsigned short* Wob) {
    size_t i = ((size_t)blockIdx.x * 256 + threadIdx.x) * 4;
    const float* src; unsigned short* dst; size_t off;
    if      (i < 4194304) { src = x;  dst = xb;  off = i; }
    else if (i < 5242880) { src = Wq; dst = Wqb; off = i - 4194304; }
    else if (i < 6291456) { src = Wk; dst = Wkb; off = i - 5242880; }
    else                  { src = Wo; dst = Wob; off = i - 6291456; }
    float4 v = *(const float4*)(src + off);
    ushort4 o;
    o.x = f2bf(v.x); o.y = f2bf(v.y); o.z = f2bf(v.z); o.w = f2bf(v.w);
    *(ushort4*)(dst + off) = o;
}

// Q = Xb @ Wq^T + bq, K = Xb @ Wk^T + bk  (blockIdx.z selects Q or K).
__global__ __launch_bounds__(256) void proj_kernel(
        const bf16* __restrict__ X, const bf16* __restrict__ Wqb,
        const bf16* __restrict__ Wkb, const float* __restrict__ bq,
        const float* __restrict__ bk, unsigned short* Qb, unsigned short* Kb) {
    __shared__ bf16 As[128 * 64];
    __shared__ bf16 Bs[128 * 64];
    const int tid = threadIdx.x, wid = tid >> 6, lane = tid & 63;
    const int wm = wid >> 1, wn = wid & 1;
    const int n0 = blockIdx.x * 128, m0 = blockIdx.y * 128;
    const bf16*  W    = blockIdx.z ? Wkb : Wqb;
    const float* bias = blockIdx.z ? bk  : bq;
    unsigned short* Out = blockIdx.z ? Kb : Qb;

    f32x4 acc[4][4];
    const f32x4 z4 = {0.f, 0.f, 0.f, 0.f};
#pragma unroll
    for (int i = 0; i < 4; ++i)
#pragma unroll
        for (int j = 0; j < 4; ++j) acc[i][j] = z4;

    for (int kt = 0; kt < 16; ++kt) {
        stage128x64(X + (size_t)m0 * 1024 + kt * 64, 1024, As, tid);
        stage128x64(W + (size_t)n0 * 1024 + kt * 64, 1024, Bs, tid);
        __syncthreads();
        mma_tile(As, Bs, wm, wn, lane, acc);
        __syncthreads();
    }

    const int q = lane >> 4, lm = lane & 15;
#pragma unroll
    for (int j = 0; j < 4; ++j) {
        const int col = n0 + wn * 64 + j * 16 + lm;
        const float bc = bias[col];
#pragma unroll
        for (int i = 0; i < 4; ++i)
#pragma unroll
            for (int r = 0; r < 4; ++r) {
                const int row = m0 + wm * 64 + i * 16 + q * 4 + r;
                Out[(size_t)row * 1024 + col] = f2bf(acc[i][j][r] + bc);
            }
    }
}

// One block per (b, h, 128-row i-tile). Sweeps all 1024 keys in 8 chunks of
// 128 with a double-buffered K-tile (1 barrier/chunk; staging overlaps the
// exp/mask epilogue). Q-tile staged ONCE. Row sums accumulate in registers
// across the sweep -> Z written directly (no atomics, no pre-zeroing).
__global__ __launch_bounds__(256) void scores_kernel(
        const bf16* __restrict__ Qb, const bf16* __restrict__ Kb,
        const int* __restrict__ mask, unsigned short* Pun, float* Z) {
    __shared__ bf16 As[128 * 64];
    __shared__ bf16 Bs[2][128 * 64];
    __shared__ float Zs[2][128];
    const int tid = threadIdx.x, wid = tid >> 6, lane = tid & 63;
    const int wm = wid >> 1, wn = wid & 1;
    const int i0 = blockIdx.x * 128;
    const int h = blockIdx.y & 15, b = blockIdx.y >> 4;
    const int q = lane >> 4, lm = lane & 15;

    const bf16* Qh = Qb + ((size_t)(b * 1024 + i0)) * 1024 + h * 64;
    const bf16* Kh = Kb + ((size_t)(b * 1024)) * 1024 + h * 64;

    stage128x64(Qh, 1024, As, tid);
    stage128x64(Kh, 1024, Bs[0], tid);

    float rs[4][4];
#pragma unroll
    for (int i = 0; i < 4; ++i)
#pragma unroll
        for (int r = 0; r < 4; ++r) rs[i][r] = 0.f;

    for (int jt = 0; jt < 8; ++jt) {
        __syncthreads();   // Bs[jt&1] staged; all waves done reading Bs[(jt+1)&1]
        if (jt < 7)
            stage128x64(Kh + (size_t)(jt + 1) * 128 * 1024, 1024, Bs[(jt + 1) & 1], tid);

        f32x4 acc[4][4];
        const f32x4 z4 = {0.f, 0.f, 0.f, 0.f};
#pragma unroll
        for (int i = 0; i < 4; ++i)
#pragma unroll
            for (int j = 0; j < 4; ++j) acc[i][j] = z4;
        mma_tile(As, Bs[jt & 1], wm, wn, lane, acc);

#pragma unroll
        for (int i = 0; i < 4; ++i)
#pragma unroll
            for (int r = 0; r < 4; ++r) {
                const int ii = i0 + wm * 64 + i * 16 + q * 4 + r;
                const size_t mrow = (size_t)b * 16384 + (size_t)ii * 16 + h;
#pragma unroll
                for (int j = 0; j < 4; ++j) {
                    const int jj = jt * 128 + wn * 64 + j * 16 + lm;
                    const float s = acc[i][j][r] * 0.125f;
                    const int mk = mask[((size_t)b * 1024 + ii) * 1024 + jj];
                    const float p = mk ? __expf(s) : 0.f;
                    Pun[mrow * 1024 + jj] = f2bf(p);
                    rs[i][r] += p;
                }
            }
    }

    // reduce row sums: 16 lanes -> wn pair via LDS -> global Z
#pragma unroll
    for (int i = 0; i < 4; ++i)
#pragma unroll
        for (int r = 0; r < 4; ++r) {
            float v = rs[i][r];
            for (int off = 1; off < 16; off <<= 1) v += __shfl_xor(v, off, 16);
            if (lm == 0) Zs[wn][wm * 64 + i * 16 + q * 4 + r] = v;
        }
    __syncthreads();
    if (tid < 128) {
        const size_t m = (size_t)b * 16384 + (size_t)(i0 + tid) * 16 + h;
        Z[m] = Zs[0][tid] + Zs[1][tid];
    }
}

// out = (Pun @ Wo^T) / Z[m] + bo[e].  M=65536, N=1024, K=1024.
// 256x128 tile, 4 waves: wave w owns rows w*64..+63 x all 128 cols
// (acc 4x8). Per K-step: 256 MFMA vs 96 ds_read_b128 -> MFMA-bound ratio
// (R2's 128x128 was LDS-pipe-bound at 128 MFMA vs 64 ds_read).
__global__ __launch_bounds__(256) void out_gemm_kernel(
        const bf16* __restrict__ Pun, const bf16* __restrict__ Wob,
        const float* __restrict__ Z, const float* __restrict__ bo,
        float* __restrict__ out) {
    __shared__ bf16 As[256 * 64];
    __shared__ bf16 Bs[128 * 64];
    const int tid = threadIdx.x, w = tid >> 6, lane = tid & 63;
    const int lm = lane & 15, g = lane >> 4;
    const int m0 = (blockIdx.x >> 3) * 256;
    const int n0 = (blockIdx.x & 7) * 128;

    f32x4 acc[4][8];
    const f32x4 z4 = {0.f, 0.f, 0.f, 0.f};
#pragma unroll
    for (int i = 0; i < 4; ++i)
#pragma unroll
        for (int j = 0; j < 8; ++j) acc[i][j] = z4;

    for (int kt = 0; kt < 16; ++kt) {
        stage128x64(Pun + (size_t)m0 * 1024 + kt * 64, 1024, As, tid);
        stage128x64(Pun + (size_t)(m0 + 128) * 1024 + kt * 64, 1024, As + 128 * 64, tid);
        stage128x64(Wob + (size_t)n0 * 1024 + kt * 64, 1024, Bs, tid);
        __syncthreads();
#pragma unroll
        for (int ks = 0; ks < 2; ++ks) {
            const int c = ks * 4 + g;
            bf16x8 a[4], b[8];
#pragma unroll
            for (int t = 0; t < 4; ++t) {
                const int row = w * 64 + t * 16 + lm;
                a[t] = *(const bf16x8*)(As + row * 64 + ((c ^ (row & 7)) << 3));
            }
#pragma unroll
            for (int t = 0; t < 8; ++t) {
                const int row = t * 16 + lm;
                b[t] = *(const bf16x8*)(Bs + row * 64 + ((c ^ (row & 7)) << 3));
            }
#pragma unroll
            for (int i = 0; i < 4; ++i)
#pragma unroll
                for (int j = 0; j < 8; ++j)
                    acc[i][j] = __builtin_amdgcn_mfma_f32_16x16x32_bf16(a[i], b[j], acc[i][j], 0, 0, 0);
        }
        __syncthreads();
    }

#pragma unroll
    for (int i = 0; i < 4; ++i)
#pragma unroll
        for (int r = 0; r < 4; ++r) {
            const int row = m0 + w * 64 + i * 16 + g * 4 + r;
            const float zi = 1.0f / Z[row];
#pragma unroll
            for (int j = 0; j < 8; ++j) {
                const int col = n0 + j * 16 + lm;
                out[(size_t)row * 1024 + col] = acc[i][j][r] * zi + bo[col];
            }
        }
}

// ---------------------------------------------------------------- launch

extern "C" void kernel_launch(void* const* d_in, const int* in_sizes, int n_in,
                              void* d_out, int out_size, void* d_ws, size_t ws_size,
                              hipStream_t stream) {
    (void)in_sizes; (void)n_in; (void)out_size; (void)ws_size;
    const float* x    = (const float*)d_in[0];
    const int*   mask = (const int*)d_in[1];
    const float* Wq   = (const float*)d_in[2];
    const float* bq   = (const float*)d_in[3];
    const float* Wk   = (const float*)d_in[4];
    const float* bk   = (const float*)d_in[5];
    // d_in[6]=Wv, d_in[7]=bv: computed-then-discarded in reference; skipped.
    const float* Wo   = (const float*)d_in[8];
    const float* bo   = (const float*)d_in[9];

    char* ws = (char*)d_ws;
    bf16*  xb  = (bf16*)(ws);                    //  8 MB  x bf16
    bf16*  Wqb = (bf16*)(ws + 8388608);          //  2 MB
    bf16*  Wkb = (bf16*)(ws + 10485760);         //  2 MB
    bf16*  Wob = (bf16*)(ws + 12582912);         //  2 MB
    bf16*  Qb  = (bf16*)(ws + 14680064);         //  8 MB
    bf16*  Kb  = (bf16*)(ws + 23068672);         //  8 MB
    float* Z   = (float*)(ws + 31457280);        // 256 KB
    bf16*  Pun = (bf16*)(ws + 31981568);         // 128 MB (end ~158.5 MB)

    convert_kernel<<<7168, 256, 0, stream>>>(x, Wq, Wk, Wo,
        (unsigned short*)xb, (unsigned short*)Wqb, (unsigned short*)Wkb,
        (unsigned short*)Wob);
    proj_kernel<<<dim3(8, 32, 2), 256, 0, stream>>>(xb, Wqb, Wkb, bq, bk,
        (unsigned short*)Qb, (unsigned short*)Kb);
    scores_kernel<<<dim3(8, 64), 256, 0, stream>>>(Qb, Kb, mask,
        (unsigned short*)Pun, Z);
    out_gemm_kernel<<<2048, 256, 0, stream>>>(Pun, Wob, Z, bo, (float*)d_out);
}